// Round 4
// baseline (501.289 us; speedup 1.0000x reference)
//
#include <hip/hip_runtime.h>

#define BATCH   1024
#define IDIM    256
#define ODIM    256
#define GRIDSZ  300

#define BM      64
#define BN      128
#define MT      16     // 1024/BM
#define NT      2      // 256/BN
#define KS_     64     // K-splits over i
#define IPW     4      // i per block = IDIM/KS_
#define GS_STEPS 19    // g-chunks of 16 (k=1..304, tail zero-padded)
#define NSTEPS  (IPW*GS_STEPS)   // 76
#define AP      40     // LDS pitch in shorts (80 B = 5 quad-groups, odd -> conflict-free b128)
#define B_OFF   2560   // shorts: B panel after A panel (64*40)
#define HALF_LDS 7680  // shorts per buffer: 64*40 + 128*40
#define INV2PI  0.15915494309189535f

typedef __attribute__((ext_vector_type(8))) short  short8;
typedef __attribute__((ext_vector_type(4))) float  f32x4;
typedef __attribute__((ext_vector_type(4))) unsigned int u32x4;

// bf16 pair pack: round-half-up (add 0x8000) + v_perm byte select. 3 VALU ops.
// low16 = cos plane (k even), high16 = sin plane (k odd).
__device__ __forceinline__ unsigned pk(float c, float s) {
  unsigned a = __float_as_uint(c) + 0x8000u;
  unsigned b = __float_as_uint(s) + 0x8000u;
  return __builtin_amdgcn_perm(b, a, 0x07060302u);
}

// (c,s) *= (C,S)
__device__ __forceinline__ void rot(float& c, float& s, float C, float S) {
  float t1 = s * S;
  float t2 = c * S;
  float cn = __builtin_fmaf(c, C, -t1);
  s = __builtin_fmaf(s, C, t2);
  c = cn;
}

// cos/sin of 2*pi*rev via v_fract + v_cos (revolutions; exact range reduction)
__device__ __forceinline__ void cossin(float rev, float& c, float& s) {
  c = __builtin_amdgcn_cosf(__builtin_amdgcn_fractf(rev));
  s = __builtin_amdgcn_cosf(__builtin_amdgcn_fractf(rev - 0.25f));
}

__global__ void init_out(const float* __restrict__ bias, float* __restrict__ out) {
  const int idx = blockIdx.x * 256 + threadIdx.x;
  out[idx] = bias[idx & (ODIM - 1)];
}

__global__ __launch_bounds__(256, 5) void fkan_gemm(
    const float* __restrict__ x, const float* __restrict__ fc,
    float* __restrict__ out) {
  // double-buffered: 2 x (A 64x40 + B 128x40) shorts = 30720 B -> 5 blocks/CU
  __shared__ alignas(16) short lds[2 * HALF_LDS];

  const int tid = threadIdx.x;
  const int id  = blockIdx.x;
  // swizzle: the 16 m-siblings of one (n,ks) share id%8 -> same XCD and are
  // consecutive dispatches there -> B slice (1.23 MB) reused out of XCD-L2.
  const int z = id & 7, q = id >> 3;
  const int m = q & 15, w = q >> 4;        // m 0..15, w 0..15
  const int c_ = (w << 3) | z;             // 0..127
  const int ks = c_ >> 1, n = c_ & 1;

  const int wave = tid >> 6, lane = tid & 63;
  const int wm = wave >> 1, wn = wave & 1;  // 2x2 wave grid, 32x64 tile/wave
  const int fr = lane & 15, fq = lane >> 4;

  const int rowA = tid >> 2, q8 = tid & 3;  // A staging: 64 rows x 4 k-pair quads
  const int rowB = tid >> 1, hB = tid & 1;  // B staging: 128 rows x 2 k-halves

  const float* xrow = x + (size_t)(m * BM + rowA) * IDIM + ks * IPW;
  const float* b0 = fc + ((size_t)(n * BN + rowB) * IDIM + ks * IPW) * GRIDSZ;
  const float* b1 = b0 + (size_t)ODIM * IDIM * GRIDSZ;

  const int AwrO = rowA * AP + q8 * 8;
  const int BwrO = B_OFF + rowB * AP + hB * 16;
  const int ArdO = (wm * 32 + fr) * AP + fq * 8;
  const int BrdO = B_OFF + (wn * 64 + fr) * AP + fq * 8;

  f32x4 acc[2][4];
#pragma unroll
  for (int a_ = 0; a_ < 2; ++a_)
#pragma unroll
    for (int b_ = 0; b_ < 4; ++b_)
      acc[a_][b_] = (f32x4){0.f, 0.f, 0.f, 0.f};

  // ---- prologue: seed recurrence, emit step 0, stage into buffer 0 ----
  float r1c, r1s, r16c, r16s, sc, ss, xr;
  xr = xrow[0] * INV2PI;
  cossin(xr, r1c, r1s);                       // rotation by delta-k = 1
  cossin(16.0f * xr, r16c, r16s);             // rotation by delta-k = 16 (per step)
  cossin((float)(q8 * 4 + 1) * xr, sc, ss);   // state at k = q8*4+1

  unsigned ad[4];
  {
    float c = sc, s = ss;
    ad[0] = pk(c, s);
#pragma unroll
    for (int u = 1; u < 4; ++u) { rot(c, s, r1c, r1s); ad[u] = pk(c, s); }
  }
  unsigned bw[8];
  {
    const int gb = hB * 8;
    f32x4 L0a = *(const f32x4*)(b0 + gb);
    f32x4 L0b = *(const f32x4*)(b0 + gb + 4);
    f32x4 L1a = *(const f32x4*)(b1 + gb);
    f32x4 L1b = *(const f32x4*)(b1 + gb + 4);
    bw[0] = pk(L0a.x, L1a.x); bw[1] = pk(L0a.y, L1a.y);
    bw[2] = pk(L0a.z, L1a.z); bw[3] = pk(L0a.w, L1a.w);
    bw[4] = pk(L0b.x, L1b.x); bw[5] = pk(L0b.y, L1b.y);
    bw[6] = pk(L0b.z, L1b.z); bw[7] = pk(L0b.w, L1b.w);
  }
  *(u32x4*)&lds[AwrO]     = (u32x4){ad[0], ad[1], ad[2], ad[3]};
  *(u32x4*)&lds[BwrO]     = (u32x4){bw[0], bw[1], bw[2], bw[3]};
  *(u32x4*)&lds[BwrO + 8] = (u32x4){bw[4], bw[5], bw[6], bw[7]};

  int il = 0, gs = 0, soff = 0;

#pragma unroll 2
  for (int S = 0; S < NSTEPS; ++S) {
    const short* bufr = lds + (S & 1) * HALF_LDS;
    short* bufw = lds + ((S + 1) & 1) * HALF_LDS;
    __syncthreads();   // single barrier/step: writes(S) [prev iter] before reads(S)

    // ---- fragment reads for step S ----
    short8 aF0 = *(const short8*)(bufr + ArdO);
    short8 aF1 = *(const short8*)(bufr + ArdO + 16 * AP);
    short8 bF0 = *(const short8*)(bufr + BrdO);
    short8 bF1 = *(const short8*)(bufr + BrdO + 16 * AP);
    short8 bF2 = *(const short8*)(bufr + BrdO + 32 * AP);
    short8 bF3 = *(const short8*)(bufr + BrdO + 48 * AP);

    // ---- issue next-step B loads early (latency overlaps MFMA + A-compute) ----
    int gsn = gs + 1, iln = il;
    if (gsn == GS_STEPS) { gsn = 0; iln = (il + 1) & (IPW - 1); }
    const bool newil = (gsn == 0);
    const int soffn = newil ? iln * GRIDSZ : soff + 16;
    const int gb = soffn + hB * 8;
    // gs=18,hB=1: second quad would read g=300..303 -> clamp (A-side zeros kill it)
    const int o2 = gb + (((gsn == 18) & hB) ? 0 : 4);
    f32x4 L0a = *(const f32x4*)(b0 + gb);
    f32x4 L0b = *(const f32x4*)(b0 + o2);
    f32x4 L1a = *(const f32x4*)(b1 + gb);
    f32x4 L1b = *(const f32x4*)(b1 + o2);

    // ---- MFMA (hand-unrolled) ----
    acc[0][0] = __builtin_amdgcn_mfma_f32_16x16x32_bf16(aF0, bF0, acc[0][0], 0, 0, 0);
    acc[1][0] = __builtin_amdgcn_mfma_f32_16x16x32_bf16(aF1, bF0, acc[1][0], 0, 0, 0);
    acc[0][1] = __builtin_amdgcn_mfma_f32_16x16x32_bf16(aF0, bF1, acc[0][1], 0, 0, 0);
    acc[1][1] = __builtin_amdgcn_mfma_f32_16x16x32_bf16(aF1, bF1, acc[1][1], 0, 0, 0);
    acc[0][2] = __builtin_amdgcn_mfma_f32_16x16x32_bf16(aF0, bF2, acc[0][2], 0, 0, 0);
    acc[1][2] = __builtin_amdgcn_mfma_f32_16x16x32_bf16(aF1, bF2, acc[1][2], 0, 0, 0);
    acc[0][3] = __builtin_amdgcn_mfma_f32_16x16x32_bf16(aF0, bF3, acc[0][3], 0, 0, 0);
    acc[1][3] = __builtin_amdgcn_mfma_f32_16x16x32_bf16(aF1, bF3, acc[1][3], 0, 0, 0);

    // ---- emit A(S+1) (trans/VALU overlaps matrix pipe across waves) ----
    if (newil) {
      xr = xrow[iln] * INV2PI;
      cossin(xr, r1c, r1s);
      cossin(16.0f * xr, r16c, r16s);
      cossin((float)(q8 * 4 + 1) * xr, sc, ss);
    } else {
      rot(sc, ss, r16c, r16s);   // advance state by delta-g = 16
    }
    {
      float c = sc, s = ss;
      ad[0] = pk(c, s);
#pragma unroll
      for (int u = 1; u < 4; ++u) { rot(c, s, r1c, r1s); ad[u] = pk(c, s); }
    }
    if ((gsn == 18) & (q8 == 3)) { ad[0] = 0u; ad[1] = 0u; ad[2] = 0u; ad[3] = 0u; }

    // ---- pack B(S+1), stage both into the alternate buffer ----
    bw[0] = pk(L0a.x, L1a.x); bw[1] = pk(L0a.y, L1a.y);
    bw[2] = pk(L0a.z, L1a.z); bw[3] = pk(L0a.w, L1a.w);
    bw[4] = pk(L0b.x, L1b.x); bw[5] = pk(L0b.y, L1b.y);
    bw[6] = pk(L0b.z, L1b.z); bw[7] = pk(L0b.w, L1b.w);

    *(u32x4*)&bufw[AwrO]     = (u32x4){ad[0], ad[1], ad[2], ad[3]};
    *(u32x4*)&bufw[BwrO]     = (u32x4){bw[0], bw[1], bw[2], bw[3]};
    *(u32x4*)&bufw[BwrO + 8] = (u32x4){bw[4], bw[5], bw[6], bw[7]};

    il = iln; gs = gsn; soff = soffn;
  }

  // ---- epilogue: C/D layout col=lane&15, row=(lane>>4)*4+reg [m89]; K-split fp32 atomics
  const int ob = m * BM + wm * 32 + fq * 4;
  const int oj = n * BN + wn * 64 + fr;
#pragma unroll
  for (int tI = 0; tI < 2; ++tI)
#pragma unroll
    for (int tJ = 0; tJ < 4; ++tJ) {
      float* dst = out + (size_t)(ob + tI * 16) * ODIM + (oj + tJ * 16);
#pragma unroll
      for (int rr = 0; rr < 4; ++rr)
        unsafeAtomicAdd(dst + rr * ODIM, acc[tI][tJ][rr]);
    }
}

extern "C" void kernel_launch(void* const* d_in, const int* in_sizes, int n_in,
                              void* d_out, int out_size, void* d_ws, size_t ws_size,
                              hipStream_t stream) {
  const float* x    = (const float*)d_in[0];
  const float* fc   = (const float*)d_in[1];
  const float* bias = (const float*)d_in[2];
  float* out = (float*)d_out;

  init_out<<<dim3(BATCH * ODIM / 256), dim3(256), 0, stream>>>(bias, out);
  fkan_gemm<<<dim3(MT * NT * KS_), dim3(256), 0, stream>>>(x, fc, out);
}

// Round 5
// 500.091 us; speedup vs baseline: 1.0024x; 1.0024x over previous
//
#include <hip/hip_runtime.h>

#define BATCH   1024
#define IDIM    256
#define ODIM    256
#define GRIDSZ  300
#define KS_     64     // K-splits over i
#define IPW     4      // i per block = IDIM/KS_
#define CHUNKS  19     // g-chunks of 16 (k=1..304, tail zeroed)
#define INV2PI  0.15915494309189535f

typedef __attribute__((ext_vector_type(8))) short  short8;
typedef __attribute__((ext_vector_type(4))) float  f32x4;
typedef __attribute__((ext_vector_type(4))) unsigned int u32x4;

// bf16 pair pack: round-half-up + v_perm byte select (3 VALU ops).
// result = (hi16 of s) << 16 | (hi16 of c): cos -> low16 (even k), sin -> high16 (odd k).
__device__ __forceinline__ unsigned pk(float c, float s) {
  unsigned a = __float_as_uint(c) + 0x8000u;
  unsigned b = __float_as_uint(s) + 0x8000u;
  return __builtin_amdgcn_perm(b, a, 0x07060302u);
}

// (c,s) *= (C,S)  — 2 mul + 2 fma
__device__ __forceinline__ void rot(float& c, float& s, float C, float S) {
  float t1 = s * S, t2 = c * S;
  float cn = __builtin_fmaf(c, C, -t1);
  s = __builtin_fmaf(s, C, t2);
  c = cn;
}

// cos/sin of 2*pi*rev via v_fract + v_cos (revolutions; exact range reduction)
__device__ __forceinline__ void cossin(float rev, float& c, float& s) {
  c = __builtin_amdgcn_cosf(__builtin_amdgcn_fractf(rev));
  s = __builtin_amdgcn_cosf(__builtin_amdgcn_fractf(rev - 0.25f));
}

__global__ void init_out(const float* __restrict__ bias, float* __restrict__ out) {
  const int idx = blockIdx.x * 256 + threadIdx.x;
  out[idx] = bias[idx & (ODIM - 1)];
}

// No LDS, no barriers: A generated in registers in MFMA A-fragment layout via
// rotation recurrence; B loaded global->register in B-fragment layout (L2-served);
// 16 MFMA per BK=32 step; K-split partial sums via fp32 HW atomics.
__global__ __launch_bounds__(256, 3) void fkan(
    const float* __restrict__ x, const float* __restrict__ fc,
    float* __restrict__ out) {
  const int tid = threadIdx.x, id = blockIdx.x;
  // Dispatch swizzle: XCD = id&7; the 4 m-siblings of one (n,ks) are consecutive
  // on that XCD -> shared B slice stays L2-hot.
  const int z = id & 7;
  const int m = (id >> 3) & 3;           // 0..3  (M/256)
  const int nk = (id >> 5) * 8 + z;      // 0..255
  const int n  = nk & 3;                 // 0..3  (N/64)
  const int ks = nk >> 2;                // 0..63

  const int wave = tid >> 6, lane = tid & 63;
  const int fr = lane & 15, fq = lane >> 4;
  const int mbase = m * 256 + wave * 64;   // block: 4 waves stacked along M
  const int nbase = n * 64;

  f32x4 acc[4][4];
#pragma unroll
  for (int a_ = 0; a_ < 4; ++a_)
#pragma unroll
    for (int b_ = 0; b_ < 4; ++b_)
      acc[a_][b_] = (f32x4){0.f, 0.f, 0.f, 0.f};

  float r1c[4], r1s[4], r16c[4], r16s[4], sc_[4], ss_[4];
  f32x4 B0[4], B1[4];
  unsigned bF[4][4];
  int voff[4];

  const float* b1base = fc + (size_t)ODIM * IDIM * GRIDSZ;

#pragma unroll 1
  for (int il = 0; il < IPW; ++il) {
    const int i = ks * IPW + il;
    // ---- seed A recurrence per m-frag: state at g = fq*4 (k = fq*4+1) ----
#pragma unroll
    for (int tI = 0; tI < 4; ++tI) {
      float xr = x[(size_t)(mbase + tI * 16 + fr) * IDIM + i] * INV2PI;
      cossin(xr, r1c[tI], r1s[tI]);                   // delta-k = 1
      cossin(16.0f * xr, r16c[tI], r16s[tI]);         // delta-k = 16 (per chunk)
      cossin((float)(fq * 4 + 1) * xr, sc_[tI], ss_[tI]);
    }
    // ---- issue B loads for chunk 0 ----
#pragma unroll
    for (int tJ = 0; tJ < 4; ++tJ) {
      voff[tJ] = ((nbase + tJ * 16 + fr) * IDIM + i) * GRIDSZ + fq * 4;
      B0[tJ] = *(const f32x4*)(fc + voff[tJ]);
      B1[tJ] = *(const f32x4*)(b1base + voff[tJ]);
    }

#pragma unroll 1
    for (int chunk = 0; chunk < CHUNKS; ++chunk) {
      // ---- pack B(chunk) from in-flight loads (vmcnt wait lands here) ----
#pragma unroll
      for (int tJ = 0; tJ < 4; ++tJ) {
        bF[tJ][0] = pk(B0[tJ].x, B1[tJ].x);
        bF[tJ][1] = pk(B0[tJ].y, B1[tJ].y);
        bF[tJ][2] = pk(B0[tJ].z, B1[tJ].z);
        bF[tJ][3] = pk(B0[tJ].w, B1[tJ].w);
      }
      // ---- issue B loads for chunk+1 (full step of latency cover) ----
      if (chunk < CHUNKS - 1) {
        // chunk 18, fq=3 would read g=300..303 (OOB): clamp to 296 (A zeros kill it)
        const int sub = ((chunk == CHUNKS - 2) & (fq == 3)) ? 4 : 0;
#pragma unroll
        for (int tJ = 0; tJ < 4; ++tJ) {
          voff[tJ] += 16;
          const int vu = voff[tJ] - sub;
          B0[tJ] = *(const f32x4*)(fc + vu);
          B1[tJ] = *(const f32x4*)(b1base + vu);
        }
      }
      // chunk 18 pad lanes (g=300..303): zero state -> pk(0,0)==0 -> A contributes 0
      if (chunk == CHUNKS - 1) {
        if (fq == 3) {
#pragma unroll
          for (int tI = 0; tI < 4; ++tI) { sc_[tI] = 0.0f; ss_[tI] = 0.0f; }
        }
      }
      // ---- produce A frags on the fly + MFMA ----
#pragma unroll
      for (int tI = 0; tI < 4; ++tI) {
        float c = sc_[tI], s = ss_[tI];
        unsigned a0 = pk(c, s);
        rot(c, s, r1c[tI], r1s[tI]); unsigned a1 = pk(c, s);
        rot(c, s, r1c[tI], r1s[tI]); unsigned a2 = pk(c, s);
        rot(c, s, r1c[tI], r1s[tI]); unsigned a3 = pk(c, s);
        rot(sc_[tI], ss_[tI], r16c[tI], r16s[tI]);   // advance state by delta-g=16
        short8 aV = __builtin_bit_cast(short8, (u32x4){a0, a1, a2, a3});
#pragma unroll
        for (int tJ = 0; tJ < 4; ++tJ) {
          short8 bV = __builtin_bit_cast(short8,
              (u32x4){bF[tJ][0], bF[tJ][1], bF[tJ][2], bF[tJ][3]});
          acc[tI][tJ] = __builtin_amdgcn_mfma_f32_16x16x32_bf16(aV, bV, acc[tI][tJ], 0, 0, 0);
        }
      }
    }
  }

  // ---- epilogue: C/D layout col=lane&15, row=(lane>>4)*4+reg [m89]; K-split fp32 atomics
  const int ob = mbase + fq * 4;
  const int oj = nbase + fr;
#pragma unroll
  for (int tI = 0; tI < 4; ++tI)
#pragma unroll
    for (int tJ = 0; tJ < 4; ++tJ) {
      float* dst = out + (size_t)(ob + tI * 16) * ODIM + (oj + tJ * 16);
#pragma unroll
      for (int rr = 0; rr < 4; ++rr)
        unsafeAtomicAdd(dst + rr * ODIM, acc[tI][tJ][rr]);
    }
}

extern "C" void kernel_launch(void* const* d_in, const int* in_sizes, int n_in,
                              void* d_out, int out_size, void* d_ws, size_t ws_size,
                              hipStream_t stream) {
  const float* x    = (const float*)d_in[0];
  const float* fc   = (const float*)d_in[1];
  const float* bias = (const float*)d_in[2];
  float* out = (float*)d_out;

  init_out<<<dim3(BATCH * ODIM / 256), dim3(256), 0, stream>>>(bias, out);
  fkan<<<dim3(4 * 4 * KS_), dim3(256), 0, stream>>>(x, fc, out);
}

// Round 6
// 369.926 us; speedup vs baseline: 1.3551x; 1.3519x over previous
//
#include <hip/hip_runtime.h>

#define BATCH   1024
#define IDIM    256
#define ODIM    256
#define GRIDSZ  300
#define GP      304    // padded g (dwords per (j,i) row in W), 304 = 19*16
#define KS_     64     // K-splits over i
#define IPW     4      // i per block = IDIM/KS_
#define CHUNKS  19     // g-chunks of 16 pairs per i
#define NSTEPS  (IPW*CHUNKS)   // 76
#define INV2PI  0.15915494309189535f

typedef __attribute__((ext_vector_type(8))) short  short8;
typedef __attribute__((ext_vector_type(4))) float  f32x4;
typedef __attribute__((ext_vector_type(4))) unsigned int u32x4;

// bf16 pair pack: round-half-up + v_perm byte select (3 VALU ops).
// low16 = c (even k = cos plane), high16 = s (odd k = sin plane).
__device__ __forceinline__ unsigned pk(float c, float s) {
  unsigned a = __float_as_uint(c) + 0x8000u;
  unsigned b = __float_as_uint(s) + 0x8000u;
  return __builtin_amdgcn_perm(b, a, 0x07060302u);
}

// (c,s) *= (C,S)
__device__ __forceinline__ void rot(float& c, float& s, float C, float S) {
  float t1 = s * S, t2 = c * S;
  float cn = __builtin_fmaf(c, C, -t1);
  s = __builtin_fmaf(s, C, t2);
  c = cn;
}

// cos/sin of 2*pi*rev via v_fract + v_cos (revolutions; exact range reduction)
__device__ __forceinline__ void cossin(float rev, float& c, float& s) {
  c = __builtin_amdgcn_cosf(__builtin_amdgcn_fractf(rev));
  s = __builtin_amdgcn_cosf(__builtin_amdgcn_fractf(rev - 0.25f));
}

__global__ void init_out(const float* __restrict__ bias, float* __restrict__ out) {
  const int idx = blockIdx.x * 256 + threadIdx.x;
  out[idx] = bias[idx & (ODIM - 1)];
}

// fc (fp32, 2 planes) -> W (bf16 pairs, dword per g, row pitch 304, g>=300 zero)
__global__ __launch_bounds__(320) void convertW(const float* __restrict__ fc,
                                                unsigned int* __restrict__ W) {
  const int row = blockIdx.x;          // j*IDIM + i
  const int t = threadIdx.x;
  if (t >= GP) return;
  unsigned w = 0u;
  if (t < GRIDSZ) {
    const float c0 = fc[(size_t)row * GRIDSZ + t];
    const float c1 = fc[(size_t)ODIM * IDIM * GRIDSZ + (size_t)row * GRIDSZ + t];
    w = pk(c0, c1);
  }
  W[(size_t)row * GP + t] = w;
}

// A generated in registers (rotation recurrence, MFMA A-frag layout).
// B: preconverted bf16 pairs, staged via 4KB LDS double-buffer shared by the
// block's 4 waves (each wave stages one dwordx4 + one ds_write_b128 per chunk).
// One barrier/chunk; loads issued after the barrier, consumed before the next.
__global__ __launch_bounds__(256, 4) void fkan2(
    const float* __restrict__ x, const unsigned int* __restrict__ W,
    float* __restrict__ out) {
  __shared__ alignas(16) unsigned int Blds[2][1024];   // 8 KB total

  const int tid = threadIdx.x, id = blockIdx.x;
  // XCD swizzle: the 4 m-siblings of one (n,ks) are consecutive on XCD id&7.
  const int z = id & 7;
  const int m = (id >> 3) & 3;           // M/256
  const int nk = (id >> 5) * 8 + z;      // 0..255
  const int n  = nk & 3;                 // N/64
  const int ks = nk >> 2;                // 0..63

  const int wave = tid >> 6, lane = tid & 63;
  const int fr = lane & 15, fq = lane >> 4;
  const int mbase = m * 256 + wave * 64;   // 4 waves stacked along M
  const int nbase = n * 64;

  f32x4 acc[4][4];
#pragma unroll
  for (int a_ = 0; a_ < 4; ++a_)
#pragma unroll
    for (int b_ = 0; b_ < 4; ++b_)
      acc[a_][b_] = (f32x4){0.f, 0.f, 0.f, 0.f};

  float r1c[4], r1s[4], r16c[4], r16s[4], sc_[4], ss_[4];

  // Running B dword offset: +16/chunk for all 76 chunks (i-row pitch 304 = 19*16).
  int bo = ((nbase + wave * 16 + fr) * IDIM + ks * IPW) * GP + fq * 4;
  const int sa = wave * 256 + lane * 4;    // this wave's staging slot (dwords)

  // prologue: stage chunk 0 into buffer 0
  u32x4 bl = *(const u32x4*)(W + bo);
  *(u32x4*)&Blds[0][sa] = bl;

  int gs = 0, il = 0;

#pragma unroll 2
  for (int S = 0; S < NSTEPS; ++S) {
    __syncthreads();   // buf[S&1] fully staged by all waves; no loads in flight

    // issue next chunk's load (consumed before the next barrier -> no drain cost)
    if (S < NSTEPS - 1) { bo += 16; bl = *(const u32x4*)(W + bo); }

    // seed A recurrence at i-boundaries (S = 0,19,38,57; block-uniform branch)
    if (gs == 0) {
      const int i = ks * IPW + il;
#pragma unroll
      for (int tI = 0; tI < 4; ++tI) {
        const float xr = x[(size_t)(mbase + tI * 16 + fr) * IDIM + i] * INV2PI;
        cossin(xr, r1c[tI], r1s[tI]);                   // delta-k = 1
        cossin(16.0f * xr, r16c[tI], r16s[tI]);         // delta-g = 16 per chunk
        cossin((float)(fq * 4 + 1) * xr, sc_[tI], ss_[tI]);
      }
    }

    // B fragments for this chunk (all 4 waves read all 4 frags; ~4-way b128)
    const unsigned int* buf = &Blds[S & 1][0];
    short8 bV0 = __builtin_bit_cast(short8, *(const u32x4*)(buf + lane * 4));
    short8 bV1 = __builtin_bit_cast(short8, *(const u32x4*)(buf + 256 + lane * 4));
    short8 bV2 = __builtin_bit_cast(short8, *(const u32x4*)(buf + 512 + lane * 4));
    short8 bV3 = __builtin_bit_cast(short8, *(const u32x4*)(buf + 768 + lane * 4));

    // A frags on the fly + MFMA (pad g>=300 handled by W's zero dwords)
#pragma unroll
    for (int tI = 0; tI < 4; ++tI) {
      float c = sc_[tI], s = ss_[tI];
      unsigned a0 = pk(c, s);
      rot(c, s, r1c[tI], r1s[tI]); unsigned a1 = pk(c, s);
      rot(c, s, r1c[tI], r1s[tI]); unsigned a2 = pk(c, s);
      rot(c, s, r1c[tI], r1s[tI]); unsigned a3 = pk(c, s);
      rot(sc_[tI], ss_[tI], r16c[tI], r16s[tI]);   // advance state by delta-g=16
      short8 aV = __builtin_bit_cast(short8, (u32x4){a0, a1, a2, a3});
      acc[tI][0] = __builtin_amdgcn_mfma_f32_16x16x32_bf16(aV, bV0, acc[tI][0], 0, 0, 0);
      acc[tI][1] = __builtin_amdgcn_mfma_f32_16x16x32_bf16(aV, bV1, acc[tI][1], 0, 0, 0);
      acc[tI][2] = __builtin_amdgcn_mfma_f32_16x16x32_bf16(aV, bV2, acc[tI][2], 0, 0, 0);
      acc[tI][3] = __builtin_amdgcn_mfma_f32_16x16x32_bf16(aV, bV3, acc[tI][3], 0, 0, 0);
    }

    // stage next chunk into the alternate buffer (vmcnt wait covered by body above)
    if (S < NSTEPS - 1) *(u32x4*)&Blds[(S + 1) & 1][sa] = bl;

    gs++; if (gs == CHUNKS) { gs = 0; ++il; }
  }

  // epilogue: C/D layout col=lane&15, row=(lane>>4)*4+reg [m89]; K-split fp32 atomics
  const int ob = mbase + fq * 4;
  const int oj = nbase + fr;
#pragma unroll
  for (int tI = 0; tI < 4; ++tI)
#pragma unroll
    for (int tJ = 0; tJ < 4; ++tJ) {
      float* dst = out + (size_t)(ob + tI * 16) * ODIM + (oj + tJ * 16);
#pragma unroll
      for (int rr = 0; rr < 4; ++rr)
        unsafeAtomicAdd(dst + rr * ODIM, acc[tI][tJ][rr]);
    }
}

// ---------------- fallback (R5 verbatim): used only if ws_size is too small ----
__global__ __launch_bounds__(256, 3) void fkan_fb(
    const float* __restrict__ x, const float* __restrict__ fc,
    float* __restrict__ out) {
  const int tid = threadIdx.x, id = blockIdx.x;
  const int z = id & 7;
  const int m = (id >> 3) & 3;
  const int nk = (id >> 5) * 8 + z;
  const int n  = nk & 3;
  const int ks = nk >> 2;
  const int wave = tid >> 6, lane = tid & 63;
  const int fr = lane & 15, fq = lane >> 4;
  const int mbase = m * 256 + wave * 64;
  const int nbase = n * 64;

  f32x4 acc[4][4];
#pragma unroll
  for (int a_ = 0; a_ < 4; ++a_)
#pragma unroll
    for (int b_ = 0; b_ < 4; ++b_)
      acc[a_][b_] = (f32x4){0.f, 0.f, 0.f, 0.f};

  float r1c[4], r1s[4], r16c[4], r16s[4], sc_[4], ss_[4];
  f32x4 B0[4], B1[4];
  unsigned bF[4][4];
  int voff[4];
  const float* b1base = fc + (size_t)ODIM * IDIM * GRIDSZ;

#pragma unroll 1
  for (int il = 0; il < IPW; ++il) {
    const int i = ks * IPW + il;
#pragma unroll
    for (int tI = 0; tI < 4; ++tI) {
      float xr = x[(size_t)(mbase + tI * 16 + fr) * IDIM + i] * INV2PI;
      cossin(xr, r1c[tI], r1s[tI]);
      cossin(16.0f * xr, r16c[tI], r16s[tI]);
      cossin((float)(fq * 4 + 1) * xr, sc_[tI], ss_[tI]);
    }
#pragma unroll
    for (int tJ = 0; tJ < 4; ++tJ) {
      voff[tJ] = ((nbase + tJ * 16 + fr) * IDIM + i) * GRIDSZ + fq * 4;
      B0[tJ] = *(const f32x4*)(fc + voff[tJ]);
      B1[tJ] = *(const f32x4*)(b1base + voff[tJ]);
    }
#pragma unroll 1
    for (int chunk = 0; chunk < CHUNKS; ++chunk) {
#pragma unroll
      for (int tJ = 0; tJ < 4; ++tJ) {
        bF[tJ][0] = pk(B0[tJ].x, B1[tJ].x);
        bF[tJ][1] = pk(B0[tJ].y, B1[tJ].y);
        bF[tJ][2] = pk(B0[tJ].z, B1[tJ].z);
        bF[tJ][3] = pk(B0[tJ].w, B1[tJ].w);
      }
      if (chunk < CHUNKS - 1) {
        const int sub = ((chunk == CHUNKS - 2) & (fq == 3)) ? 4 : 0;
#pragma unroll
        for (int tJ = 0; tJ < 4; ++tJ) {
          voff[tJ] += 16;
          const int vu = voff[tJ] - sub;
          B0[tJ] = *(const f32x4*)(fc + vu);
          B1[tJ] = *(const f32x4*)(b1base + vu);
        }
      }
      if (chunk == CHUNKS - 1) {
        if (fq == 3) {
#pragma unroll
          for (int tI = 0; tI < 4; ++tI) { sc_[tI] = 0.0f; ss_[tI] = 0.0f; }
        }
      }
#pragma unroll
      for (int tI = 0; tI < 4; ++tI) {
        float c = sc_[tI], s = ss_[tI];
        unsigned a0 = pk(c, s);
        rot(c, s, r1c[tI], r1s[tI]); unsigned a1 = pk(c, s);
        rot(c, s, r1c[tI], r1s[tI]); unsigned a2 = pk(c, s);
        rot(c, s, r1c[tI], r1s[tI]); unsigned a3 = pk(c, s);
        rot(sc_[tI], ss_[tI], r16c[tI], r16s[tI]);
        short8 aV = __builtin_bit_cast(short8, (u32x4){a0, a1, a2, a3});
#pragma unroll
        for (int tJ = 0; tJ < 4; ++tJ) {
          short8 bV = __builtin_bit_cast(short8,
              (u32x4){bF[tJ][0], bF[tJ][1], bF[tJ][2], bF[tJ][3]});
          acc[tI][tJ] = __builtin_amdgcn_mfma_f32_16x16x32_bf16(aV, bV, acc[tI][tJ], 0, 0, 0);
        }
      }
    }
  }
  const int ob = mbase + fq * 4;
  const int oj = nbase + fr;
#pragma unroll
  for (int tI = 0; tI < 4; ++tI)
#pragma unroll
    for (int tJ = 0; tJ < 4; ++tJ) {
      float* dst = out + (size_t)(ob + tI * 16) * ODIM + (oj + tJ * 16);
#pragma unroll
      for (int rr = 0; rr < 4; ++rr)
        unsafeAtomicAdd(dst + rr * ODIM, acc[tI][tJ][rr]);
    }
}

extern "C" void kernel_launch(void* const* d_in, const int* in_sizes, int n_in,
                              void* d_out, int out_size, void* d_ws, size_t ws_size,
                              hipStream_t stream) {
  const float* x    = (const float*)d_in[0];
  const float* fc   = (const float*)d_in[1];
  const float* bias = (const float*)d_in[2];
  float* out = (float*)d_out;

  init_out<<<dim3(BATCH * ODIM / 256), dim3(256), 0, stream>>>(bias, out);

  const size_t need = (size_t)ODIM * IDIM * GP * 4;   // 79.7 MB
  if (ws_size >= need) {
    unsigned int* W = (unsigned int*)d_ws;
    convertW<<<dim3(ODIM * IDIM), dim3(320), 0, stream>>>(fc, W);
    fkan2<<<dim3(4 * 4 * KS_), dim3(256), 0, stream>>>(x, W, out);
  } else {
    fkan_fb<<<dim3(4 * 4 * KS_), dim3(256), 0, stream>>>(x, fc, out);
  }
}

// Round 7
// 364.753 us; speedup vs baseline: 1.3743x; 1.0142x over previous
//
#include <hip/hip_runtime.h>

#define BATCH   1024
#define IDIM    256
#define ODIM    256
#define GRIDSZ  300
#define GP      304    // padded g (dwords per (j,i) row in W), 304 = 19*16
#define KS_     64     // K-splits over i
#define IPW     4      // i per block = IDIM/KS_
#define CHUNKS  19     // g-chunks of 16 pairs per i
#define NSTEPS  (IPW*CHUNKS)   // 76
#define INV2PI  0.15915494309189535f

typedef __attribute__((ext_vector_type(8))) short  short8;
typedef __attribute__((ext_vector_type(4))) float  f32x4;
typedef __attribute__((ext_vector_type(4))) unsigned int u32x4;

// bf16 pair pack: round-half-up + v_perm byte select (3 VALU ops).
// low16 = c (even k = cos plane), high16 = s (odd k = sin plane).
__device__ __forceinline__ unsigned pk(float c, float s) {
  unsigned a = __float_as_uint(c) + 0x8000u;
  unsigned b = __float_as_uint(s) + 0x8000u;
  return __builtin_amdgcn_perm(b, a, 0x07060302u);
}

// (c,s) *= (C,S)
__device__ __forceinline__ void rot(float& c, float& s, float C, float S) {
  float t1 = s * S, t2 = c * S;
  float cn = __builtin_fmaf(c, C, -t1);
  s = __builtin_fmaf(s, C, t2);
  c = cn;
}

// cos/sin of 2*pi*rev via v_fract + v_cos (revolutions; exact range reduction)
__device__ __forceinline__ void cossin(float rev, float& c, float& s) {
  c = __builtin_amdgcn_cosf(__builtin_amdgcn_fractf(rev));
  s = __builtin_amdgcn_cosf(__builtin_amdgcn_fractf(rev - 0.25f));
}

__global__ void init_out(const float* __restrict__ bias, float* __restrict__ out) {
  const int idx = blockIdx.x * 256 + threadIdx.x;
  out[idx] = bias[idx & (ODIM - 1)];
}

// fc (fp32, 2 planes) -> W (bf16 pairs, dword/g, row pitch 304, g>=300 zero).
// Thread-per-quad: two aligned float4 loads + one uint4 store, fully coalesced.
// (300 = 4*75 -> every row base is 16B-aligned; quad 75 is the all-pad zero store.)
__global__ __launch_bounds__(256) void convertW(const float* __restrict__ fc,
                                                unsigned int* __restrict__ W) {
  const int qid = blockIdx.x * 256 + threadIdx.x;   // 0 .. 65536*76-1
  const int row = qid / 76;                         // j*IDIM + i (magic-mul)
  const int q   = qid - row * 76;                   // quad within row, 0..75
  u32x4 w = (u32x4){0u, 0u, 0u, 0u};
  if (q < 75) {
    const float* p0 = fc + (size_t)row * GRIDSZ + q * 4;
    const float* p1 = p0 + (size_t)ODIM * IDIM * GRIDSZ;
    const f32x4 a = *(const f32x4*)p0;
    const f32x4 b = *(const f32x4*)p1;
    w = (u32x4){pk(a.x, b.x), pk(a.y, b.y), pk(a.z, b.z), pk(a.w, b.w)};
  }
  *(u32x4*)(W + (size_t)row * GP + q * 4) = w;
}

// A generated in registers (rotation recurrence, MFMA A-frag layout).
// B: preconverted bf16 pairs, staged via 4KB LDS double-buffer shared by the
// block's 4 waves (each wave stages one dwordx4 + one ds_write_b128 per chunk).
// One barrier/chunk; loads issued after the barrier, consumed before the next.
__global__ __launch_bounds__(256, 4) void fkan2(
    const float* __restrict__ x, const unsigned int* __restrict__ W,
    float* __restrict__ out) {
  __shared__ alignas(16) unsigned int Blds[2][1024];   // 8 KB total

  const int tid = threadIdx.x, id = blockIdx.x;
  // XCD swizzle: the 4 m-siblings of one (n,ks) are consecutive on XCD id&7.
  const int z = id & 7;
  const int m = (id >> 3) & 3;           // M/256
  const int nk = (id >> 5) * 8 + z;      // 0..255
  const int n  = nk & 3;                 // N/64
  const int ks = nk >> 2;                // 0..63

  const int wave = tid >> 6, lane = tid & 63;
  const int fr = lane & 15, fq = lane >> 4;
  const int mbase = m * 256 + wave * 64;   // 4 waves stacked along M
  const int nbase = n * 64;

  f32x4 acc[4][4];
#pragma unroll
  for (int a_ = 0; a_ < 4; ++a_)
#pragma unroll
    for (int b_ = 0; b_ < 4; ++b_)
      acc[a_][b_] = (f32x4){0.f, 0.f, 0.f, 0.f};

  float r1c[4], r1s[4], r16c[4], r16s[4], sc_[4], ss_[4];

  // Running B dword offset: +16/chunk for all 76 chunks (i-row pitch 304 = 19*16).
  int bo = ((nbase + wave * 16 + fr) * IDIM + ks * IPW) * GP + fq * 4;
  const int sa = wave * 256 + lane * 4;    // this wave's staging slot (dwords)

  // prologue: stage chunk 0 into buffer 0
  u32x4 bl = *(const u32x4*)(W + bo);
  *(u32x4*)&Blds[0][sa] = bl;

  int gs = 0, il = 0;

#pragma unroll 2
  for (int S = 0; S < NSTEPS; ++S) {
    __syncthreads();   // buf[S&1] fully staged by all waves; no loads in flight

    // issue next chunk's load (consumed before the next barrier -> no drain cost)
    if (S < NSTEPS - 1) { bo += 16; bl = *(const u32x4*)(W + bo); }

    // seed A recurrence at i-boundaries (S = 0,19,38,57; block-uniform branch)
    if (gs == 0) {
      const int i = ks * IPW + il;
#pragma unroll
      for (int tI = 0; tI < 4; ++tI) {
        const float xr = x[(size_t)(mbase + tI * 16 + fr) * IDIM + i] * INV2PI;
        cossin(xr, r1c[tI], r1s[tI]);                   // delta-k = 1
        cossin(16.0f * xr, r16c[tI], r16s[tI]);         // delta-g = 16 per chunk
        cossin((float)(fq * 4 + 1) * xr, sc_[tI], ss_[tI]);
      }
    }

    // B fragments for this chunk (all 4 waves read all 4 frags; ~4-way b128)
    const unsigned int* buf = &Blds[S & 1][0];
    short8 bV0 = __builtin_bit_cast(short8, *(const u32x4*)(buf + lane * 4));
    short8 bV1 = __builtin_bit_cast(short8, *(const u32x4*)(buf + 256 + lane * 4));
    short8 bV2 = __builtin_bit_cast(short8, *(const u32x4*)(buf + 512 + lane * 4));
    short8 bV3 = __builtin_bit_cast(short8, *(const u32x4*)(buf + 768 + lane * 4));

    // A frags on the fly + MFMA (pad g>=300 handled by W's zero dwords)
#pragma unroll
    for (int tI = 0; tI < 4; ++tI) {
      float c = sc_[tI], s = ss_[tI];
      unsigned a0 = pk(c, s);
      rot(c, s, r1c[tI], r1s[tI]); unsigned a1 = pk(c, s);
      rot(c, s, r1c[tI], r1s[tI]); unsigned a2 = pk(c, s);
      rot(c, s, r1c[tI], r1s[tI]); unsigned a3 = pk(c, s);
      rot(sc_[tI], ss_[tI], r16c[tI], r16s[tI]);   // advance state by delta-g=16
      short8 aV = __builtin_bit_cast(short8, (u32x4){a0, a1, a2, a3});
      acc[tI][0] = __builtin_amdgcn_mfma_f32_16x16x32_bf16(aV, bV0, acc[tI][0], 0, 0, 0);
      acc[tI][1] = __builtin_amdgcn_mfma_f32_16x16x32_bf16(aV, bV1, acc[tI][1], 0, 0, 0);
      acc[tI][2] = __builtin_amdgcn_mfma_f32_16x16x32_bf16(aV, bV2, acc[tI][2], 0, 0, 0);
      acc[tI][3] = __builtin_amdgcn_mfma_f32_16x16x32_bf16(aV, bV3, acc[tI][3], 0, 0, 0);
    }

    // stage next chunk into the alternate buffer (vmcnt wait covered by body above)
    if (S < NSTEPS - 1) *(u32x4*)&Blds[(S + 1) & 1][sa] = bl;

    gs++; if (gs == CHUNKS) { gs = 0; ++il; }
  }

  // epilogue: C/D layout col=lane&15, row=(lane>>4)*4+reg [m89]; K-split fp32 atomics
  const int ob = mbase + fq * 4;
  const int oj = nbase + fr;
#pragma unroll
  for (int tI = 0; tI < 4; ++tI)
#pragma unroll
    for (int tJ = 0; tJ < 4; ++tJ) {
      float* dst = out + (size_t)(ob + tI * 16) * ODIM + (oj + tJ * 16);
#pragma unroll
      for (int rr = 0; rr < 4; ++rr)
        unsafeAtomicAdd(dst + rr * ODIM, acc[tI][tJ][rr]);
    }
}

// ---------------- fallback (R5 verbatim): used only if ws_size is too small ----
__global__ __launch_bounds__(256, 3) void fkan_fb(
    const float* __restrict__ x, const float* __restrict__ fc,
    float* __restrict__ out) {
  const int tid = threadIdx.x, id = blockIdx.x;
  const int z = id & 7;
  const int m = (id >> 3) & 3;
  const int nk = (id >> 5) * 8 + z;
  const int n  = nk & 3;
  const int ks = nk >> 2;
  const int wave = tid >> 6, lane = tid & 63;
  const int fr = lane & 15, fq = lane >> 4;
  const int mbase = m * 256 + wave * 64;
  const int nbase = n * 64;

  f32x4 acc[4][4];
#pragma unroll
  for (int a_ = 0; a_ < 4; ++a_)
#pragma unroll
    for (int b_ = 0; b_ < 4; ++b_)
      acc[a_][b_] = (f32x4){0.f, 0.f, 0.f, 0.f};

  float r1c[4], r1s[4], r16c[4], r16s[4], sc_[4], ss_[4];
  f32x4 B0[4], B1[4];
  unsigned bF[4][4];
  int voff[4];
  const float* b1base = fc + (size_t)ODIM * IDIM * GRIDSZ;

#pragma unroll 1
  for (int il = 0; il < IPW; ++il) {
    const int i = ks * IPW + il;
#pragma unroll
    for (int tI = 0; tI < 4; ++tI) {
      float xr = x[(size_t)(mbase + tI * 16 + fr) * IDIM + i] * INV2PI;
      cossin(xr, r1c[tI], r1s[tI]);
      cossin(16.0f * xr, r16c[tI], r16s[tI]);
      cossin((float)(fq * 4 + 1) * xr, sc_[tI], ss_[tI]);
    }
#pragma unroll
    for (int tJ = 0; tJ < 4; ++tJ) {
      voff[tJ] = ((nbase + tJ * 16 + fr) * IDIM + i) * GRIDSZ + fq * 4;
      B0[tJ] = *(const f32x4*)(fc + voff[tJ]);
      B1[tJ] = *(const f32x4*)(b1base + voff[tJ]);
    }
#pragma unroll 1
    for (int chunk = 0; chunk < CHUNKS; ++chunk) {
#pragma unroll
      for (int tJ = 0; tJ < 4; ++tJ) {
        bF[tJ][0] = pk(B0[tJ].x, B1[tJ].x);
        bF[tJ][1] = pk(B0[tJ].y, B1[tJ].y);
        bF[tJ][2] = pk(B0[tJ].z, B1[tJ].z);
        bF[tJ][3] = pk(B0[tJ].w, B1[tJ].w);
      }
      if (chunk < CHUNKS - 1) {
        const int sub = ((chunk == CHUNKS - 2) & (fq == 3)) ? 4 : 0;
#pragma unroll
        for (int tJ = 0; tJ < 4; ++tJ) {
          voff[tJ] += 16;
          const int vu = voff[tJ] - sub;
          B0[tJ] = *(const f32x4*)(fc + vu);
          B1[tJ] = *(const f32x4*)(b1base + vu);
        }
      }
      if (chunk == CHUNKS - 1) {
        if (fq == 3) {
#pragma unroll
          for (int tI = 0; tI < 4; ++tI) { sc_[tI] = 0.0f; ss_[tI] = 0.0f; }
        }
      }
#pragma unroll
      for (int tI = 0; tI < 4; ++tI) {
        float c = sc_[tI], s = ss_[tI];
        unsigned a0 = pk(c, s);
        rot(c, s, r1c[tI], r1s[tI]); unsigned a1 = pk(c, s);
        rot(c, s, r1c[tI], r1s[tI]); unsigned a2 = pk(c, s);
        rot(c, s, r1c[tI], r1s[tI]); unsigned a3 = pk(c, s);
        rot(sc_[tI], ss_[tI], r16c[tI], r16s[tI]);
        short8 aV = __builtin_bit_cast(short8, (u32x4){a0, a1, a2, a3});
#pragma unroll
        for (int tJ = 0; tJ < 4; ++tJ) {
          short8 bV = __builtin_bit_cast(short8,
              (u32x4){bF[tJ][0], bF[tJ][1], bF[tJ][2], bF[tJ][3]});
          acc[tI][tJ] = __builtin_amdgcn_mfma_f32_16x16x32_bf16(aV, bV, acc[tI][tJ], 0, 0, 0);
        }
      }
    }
  }
  const int ob = mbase + fq * 4;
  const int oj = nbase + fr;
#pragma unroll
  for (int tI = 0; tI < 4; ++tI)
#pragma unroll
    for (int tJ = 0; tJ < 4; ++tJ) {
      float* dst = out + (size_t)(ob + tI * 16) * ODIM + (oj + tJ * 16);
#pragma unroll
      for (int rr = 0; rr < 4; ++rr)
        unsafeAtomicAdd(dst + rr * ODIM, acc[tI][tJ][rr]);
    }
}

extern "C" void kernel_launch(void* const* d_in, const int* in_sizes, int n_in,
                              void* d_out, int out_size, void* d_ws, size_t ws_size,
                              hipStream_t stream) {
  const float* x    = (const float*)d_in[0];
  const float* fc   = (const float*)d_in[1];
  const float* bias = (const float*)d_in[2];
  float* out = (float*)d_out;

  init_out<<<dim3(BATCH * ODIM / 256), dim3(256), 0, stream>>>(bias, out);

  const size_t need = (size_t)ODIM * IDIM * GP * 4;   // 79.7 MB
  if (ws_size >= need) {
    unsigned int* W = (unsigned int*)d_ws;
    convertW<<<dim3(ODIM * IDIM * (GP / 4) / 256), dim3(256), 0, stream>>>(fc, W);
    fkan2<<<dim3(4 * 4 * KS_), dim3(256), 0, stream>>>(x, W, out);
  } else {
    fkan_fb<<<dim3(4 * 4 * KS_), dim3(256), 0, stream>>>(x, fc, out);
  }
}